// Round 19
// baseline (70.552 us; speedup 1.0000x reference)
//
#include <hip/hip_runtime.h>
#include <hip/hip_bf16.h>
#include <cmath>

#define T_STEPS 128
#define BATCH   64
#define NI      784
#define NIP     800      // padded K (25 * 32)
#define NH      512
#define NO      10
#define M1      (T_STEPS*BATCH)       // 8192
#define NT_H    (BATCH*NH)            // 32768
#define NT_O    (BATCH*NO)            // 640
#define OUT_HALF (T_STEPS*BATCH*NO)   // 81920
#define TB      8                     // time-tile for the scan

typedef __attribute__((ext_vector_type(8))) short short8;
typedef __attribute__((ext_vector_type(4))) float f32x4;
typedef __attribute__((ext_vector_type(8))) unsigned short u16x8;

static __device__ __forceinline__ unsigned short f2b_bits(float x) {
    __hip_bfloat16 h = __float2bfloat16(x);
    return *reinterpret_cast<unsigned short*>(&h);
}
static __device__ __forceinline__ float b2f_bits(unsigned short u) {
    union { unsigned int i; float f; } v; v.i = ((unsigned int)u) << 16; return v.f;
}

// --- R8 scan body (verbatim arithmetic), shared by fused1 and scanF ---------
template <bool FINAL, int STRIDE>
__device__ __forceinline__ void flif_scan_body(const char* __restrict__ inps,
                                               float* __restrict__ hist,
                                               const float* __restrict__ cs,
                                               void* __restrict__ spikes,
                                               float* __restrict__ mems,
                                               int NT, int nid, int li, float kappa) {
    float cn_[TB];
#pragma unroll
    for (int j = 0; j < TB; ++j) cn_[j] = cs[j];

    float V = -70.f;
    unsigned dvbits = 0u;

    for (int t = 0; t < T_STEPS / TB; ++t) {
        const int n0 = t * TB;

        // episode 1: batch input reads (pinned early)
        float Ivv[TB];
#pragma unroll
        for (int i = 0; i < TB; ++i) {
            if constexpr (FINAL) Ivv[i] = ((const float*)inps)[(n0 + i) * STRIDE + li];
            else                 Ivv[i] = __bfloat162float(((const __hip_bfloat16*)inps)[(n0 + i) * STRIDE + li]);
        }
        __builtin_amdgcn_sched_barrier(0);

        float old_[TB];
#pragma unroll
        for (int i = 0; i < TB; ++i) old_[i] = 0.f;

        // old-phase: skipped (bit-exactly) while history is all +0.0
        if (__any(dvbits != 0u)) {
            for (int k0 = 0; k0 < n0; k0 += TB) {
                float hv[TB];
                unsigned sb = 0u;
#pragma unroll
                for (int kk = 0; kk < TB; ++kk) {
                    hv[kk] = hist[(k0 + kk) * STRIDE + li];
                    sb |= __float_as_uint(hv[kk]);
                }
                if (__any(sb != 0u)) {
                    const int base = n0 - k0 - (TB - 1);   // >=1; base-1 multiple of 8
                    float cw[2 * TB];                      // cw[j] = c[base-1+j]
#pragma unroll
                    for (int q = 0; q < 4; ++q) {
                        const float4 cv = *reinterpret_cast<const float4*>(cs + (base - 1) + 4 * q);
                        cw[4 * q + 0] = cv.x; cw[4 * q + 1] = cv.y;
                        cw[4 * q + 2] = cv.z; cw[4 * q + 3] = cv.w;
                    }
#pragma unroll
                    for (int kk = 0; kk < TB; ++kk) {
#pragma unroll
                        for (int i = 0; i < TB; ++i)
                            old_[i] += hv[kk] * cw[TB - kk + i];
                    }
                }
            }
        }

        // episode 2: sequential phase, pure VALU + global stores
        float dvb[TB];
#pragma unroll
        for (int i = 0; i < TB; ++i) {
            const int nm1 = n0 + i;
            const float Iv = Ivv[i];
            const float f  = (-0.025f * (V + 70.f) + Iv) * 2.0f;   // /CM, CM=0.5
            const float Vn = kappa * f + V - old_[i];
            const bool  sp = (Vn >= -50.f);
            const float Vr = sp ? -70.f : Vn;
            const float dv = Vr - V;
            dvb[i] = dv;
            dvbits |= __float_as_uint(dv);
#pragma unroll
            for (int i2 = i + 1; i2 < TB; ++i2)
                old_[i2] += dv * cn_[i2 - i];
            if (FINAL) {
                ((float*)spikes)[(size_t)nm1 * NT + nid] = sp ? 1.f : 0.f;
                mems[(size_t)nm1 * NT + nid] = Vr;
            } else {
                ((__hip_bfloat16*)spikes)[(size_t)nm1 * NT + nid] = __float2bfloat16(sp ? 1.f : 0.f);
            }
            V = Vr;
        }

        // episode 3: batch hist writes
        __builtin_amdgcn_sched_barrier(0);
#pragma unroll
        for (int i = 0; i < TB; ++i)
            hist[(n0 + i) * STRIDE + li] = dvb[i];
        __builtin_amdgcn_sched_barrier(0);
    }
}

// --- prep: ctab init + pure streaming casts (R15 b-major, no permute) -------
__global__ __launch_bounds__(256) void prep_kernel(const float* __restrict__ data,
                                                   const float* __restrict__ Wh,
                                                   __hip_bfloat16* __restrict__ Ab,
                                                   __hip_bfloat16* __restrict__ Whb,
                                                   float* __restrict__ ctab) {
    const int bid = blockIdx.x;
    if (bid == 0) {
        const int j = threadIdx.x;
        if (j < 192) {
            double a = pow((double)(j + 1), 0.8);
            double b = pow((double)j, 0.8);
            ctab[j] = (float)(a - b);
        }
        return;
    }
    if (bid <= 6400) {
        const int idx = (bid - 1) * 256 + threadIdx.x;      // < M1*200 exactly
        const int r  = idx / 200;
        const int n4 = (idx - r * 200) * 4;
        ushort4 o;
        if (n4 < NI) {
            const float4 f = *reinterpret_cast<const float4*>(data + (size_t)r * NI + n4);
            o.x = f2b_bits(f.x); o.y = f2b_bits(f.y); o.z = f2b_bits(f.z); o.w = f2b_bits(f.w);
        } else {
            o.x = o.y = o.z = o.w = 0;
        }
        *reinterpret_cast<ushort4*>(Ab + (size_t)r * NIP + n4) = o;
    } else {
        const int idx = (bid - 6401) * 256 + threadIdx.x;   // < NH*200 exactly
        const int r  = idx / 200;
        const int n4 = (idx - r * 200) * 4;
        ushort4 o;
        if (n4 < NI) {
            const float4 f = *reinterpret_cast<const float4*>(Wh + (size_t)r * NI + n4);
            o.x = f2b_bits(f.x); o.y = f2b_bits(f.y); o.z = f2b_bits(f.z); o.w = f2b_bits(f.w);
        } else {
            o.x = o.y = o.z = o.w = 0;
        }
        *reinterpret_cast<ushort4*>(Whb + (size_t)r * NIP + n4) = o;
    }
}

// ---------------------------------------------------------------------------
// FUSED: GEMM1 + hidden scan. R19 change: WAVE-PRIVATE staging -> ZERO
// barriers in the 25-iteration K-loop. Each wave stages exactly the A-rows
// (its 64) and B-rows (its 32) that it reads, into its own LDS region (A and
// B duplicated 2x across waves — extra fetches are L2-hits). No inter-wave
// LDS dependency, so each wave self-paces on its own counted vmcnt(6)
// (3-buf depth-2 pipeline: iter t issues tile t+2, waits only for t+1).
// The first barrier since the prologue is AFTER the K-loop (guards the
// hist-aliases-staging reuse, Ibuf, and cs).
// Hazard audit: buffer (t+2)%3 overwrite vs the same wave's iter t-1
// ds_reads — those reads completed behind compiler lgkmcnt before t-1's
// MFMAs, and the overwriting load is issued later in program order.
// LDS: 3 bufs x 24K (4 waves x [A 4K | B 2K]) + Ibuf 16K + cs = 88.8 KB
// -> 1 block/CU (512 blocks = two dispatch passes; waves self-pace).
// Fragments / MFMA order / outputs bit-identical to R17.
// ---------------------------------------------------------------------------
__global__ __launch_bounds__(256) void fused1_kernel(const __hip_bfloat16* __restrict__ A,
                                                     const __hip_bfloat16* __restrict__ B,
                                                     __hip_bfloat16* __restrict__ Sh,
                                                     const float* __restrict__ ctab,
                                                     float kappa) {
    __shared__ __attribute__((aligned(16))) char SMEM[89856];
    // staging: [0,72K) = buf*24K + wave*6K; A at +0 (4K), B at +4K (2K)
    __hip_bfloat16* Ibuf = (__hip_bfloat16*)(SMEM + 73728);   // [72K,88K)  [t][h]
    float*          hist = (float*)SMEM;                      // [0,32K) post-GEMM alias
    float*          cs   = (float*)(SMEM + 90112 - 1024);     // [88.75K..) within 89856? see below
    // place cs right after Ibuf: [88K, 88K+768)
    cs = (float*)(SMEM + 90112 - 2048);  // = SMEM + 88064 — inside [88K,89856) region

    const int tid  = threadIdx.x;
    const int wave = tid >> 6, lane = tid & 63;
    const int wm = wave >> 1, wn = wave & 1;     // 2x2 waves over (128 t, 64 h)
    const int b  = blockIdx.x;                   // batch element
    const int hn = blockIdx.y;                   // 64-wide neuron block
    const int lrow = lane >> 2;      // 0..15
    const int lchk = lane & 3;       // 0..3

    const int NTILES = NIP / 32;     // 25

    char* const wbuf0 = SMEM + wave * 6144;      // this wave's slice of buf 0

    // Stage tile tt into buffer buf: ONLY this wave's operand rows.
    // A: rows b*128 + wm*64 + q*16 + lrow (q=0..3), cols k0 + lchk*8
    // B: rows hn*64 + wn*32 + q*16 + lrow (q=0..1)
    auto STAGE = [&](int buf, int tt) {
        const int k0 = tt * 32;
        char* wb = wbuf0 + buf * 24576;
#pragma unroll
        for (int q = 0; q < 4; ++q) {
            const __hip_bfloat16* g = A + (size_t)(b * T_STEPS + wm * 64 + q * 16 + lrow) * NIP + k0 + lchk * 8;
            __builtin_amdgcn_global_load_lds((const __attribute__((address_space(1))) void*)g,
                                             (__attribute__((address_space(3))) void*)(wb + q * 1024),
                                             16, 0, 0);
        }
#pragma unroll
        for (int q = 0; q < 2; ++q) {
            const __hip_bfloat16* g = B + (size_t)(hn * 64 + wn * 32 + q * 16 + lrow) * NIP + k0 + lchk * 8;
            __builtin_amdgcn_global_load_lds((const __attribute__((address_space(1))) void*)g,
                                             (__attribute__((address_space(3))) void*)(wb + 4096 + q * 1024),
                                             16, 0, 0);
        }
    };

    f32x4 acc[4][2] = {};

    // prologue: stage tiles 0..1 (own loads only; no barrier needed)
    STAGE(0, 0);
    STAGE(1, 1);
    for (int j = tid; j < 192; j += 256) cs[j] = ctab[j];
    asm volatile("s_waitcnt vmcnt(0)" ::: "memory");   // own 12 loads landed
    __builtin_amdgcn_sched_barrier(0);

    for (int t = 0; t < NTILES; ++t) {
        if (t + 2 < NTILES) STAGE((t + 2) % 3, t + 2);   // depth-2, own loads

        const __hip_bfloat16* wb = (const __hip_bfloat16*)(wbuf0 + (t % 3) * 24576);
        short8 a[4], bb[2];
#pragma unroll
        for (int i = 0; i < 4; ++i)   // wave's A rows are locally 0..63: row i*16 + (lane&15)
            a[i] = *reinterpret_cast<const short8*>(wb + (i * 16 + (lane & 15)) * 32 + (lane >> 4) * 8);
#pragma unroll
        for (int j = 0; j < 2; ++j)   // wave's B rows locally 0..31 (offset 2048 elems)
            bb[j] = *reinterpret_cast<const short8*>(wb + 2048 + (j * 16 + (lane & 15)) * 32 + (lane >> 4) * 8);
#pragma unroll
        for (int i = 0; i < 4; ++i)
#pragma unroll
            for (int j = 0; j < 2; ++j)
                acc[i][j] = __builtin_amdgcn_mfma_f32_16x16x32_bf16(a[i], bb[j], acc[i][j], 0, 0, 0);

        // per-wave counted wait: tile t+1 complete; t+2 stays in flight.
        if (t + 1 < NTILES) {
            if (t <= 22) asm volatile("s_waitcnt vmcnt(6)" ::: "memory");
            else         asm volatile("s_waitcnt vmcnt(0)" ::: "memory");
            __builtin_amdgcn_sched_barrier(0);
        }
    }

    __syncthreads();   // FIRST block barrier since prologue: staging dead,
                       // cs visible, safe to alias hist over staging region.

    // I tile -> LDS bf16 (same cast as before; row=t, col=h)
    // C/D layout: col = lane&15, row = (lane>>4)*4 + reg
#pragma unroll
    for (int i = 0; i < 4; ++i) {
#pragma unroll
        for (int j = 0; j < 2; ++j) {
            const int col = wn * 32 + j * 16 + (lane & 15);
#pragma unroll
            for (int r2 = 0; r2 < 4; ++r2) {
                const int row = wm * 64 + i * 16 + (lane >> 4) * 4 + r2;
                Ibuf[row * 64 + col] = __float2bfloat16(acc[i][j][r2]);
            }
        }
    }
    __syncthreads();                             // Ibuf complete

    // hidden scan: wave 0, one thread per neuron column.
    // Store: Sh[(t*64+b)*NH + hn*64 + lane] = (Sh+b*NH)[t*(64*NH) + hn*64+lane]
    if (tid < 64) {
        flif_scan_body<false, 64>((const char*)Ibuf, hist, cs,
                                  (void*)(Sh + (size_t)b * NH), nullptr,
                                  64 * NH, hn * 64 + tid, tid, kappa);
    }
}

// --- GEMM2: Io[r][o] = sum_h S[r][h]*Wo[o][h] (R17 version) -----------------
__global__ __launch_bounds__(256) void gemm2_kernel(const __hip_bfloat16* __restrict__ S,
                                                    const float* __restrict__ Wo,
                                                    float* __restrict__ Io) {
    const int wave = threadIdx.x >> 6, lane = threadIdx.x & 63;
    const int r0 = (blockIdx.x * 4 + wave) * 4;

    float wreg[NO][8];
#pragma unroll
    for (int o = 0; o < NO; ++o) {
        const float4 w0 = *reinterpret_cast<const float4*>(Wo + (size_t)o * NH + lane * 8);
        const float4 w1 = *reinterpret_cast<const float4*>(Wo + (size_t)o * NH + lane * 8 + 4);
        wreg[o][0] = w0.x; wreg[o][1] = w0.y; wreg[o][2] = w0.z; wreg[o][3] = w0.w;
        wreg[o][4] = w1.x; wreg[o][5] = w1.y; wreg[o][6] = w1.z; wreg[o][7] = w1.w;
    }

#pragma unroll
    for (int rr = 0; rr < 4; ++rr) {
        const int r = r0 + rr;
        u16x8 raw = *reinterpret_cast<const u16x8*>(S + (size_t)r * NH + lane * 8);
        float s[8];
#pragma unroll
        for (int j = 0; j < 8; ++j) s[j] = b2f_bits(raw[j]);
#pragma unroll
        for (int o = 0; o < NO; ++o) {
            float a = 0.f;
#pragma unroll
            for (int j = 0; j < 8; ++j) a += s[j] * wreg[o][j];
#pragma unroll
            for (int off = 32; off; off >>= 1) a += __shfl_xor(a, off);
            if (lane == o) Io[(size_t)r * NO + o] = a;
        }
    }
}

// --- final scan (R17 version: LDS-staged f32 input, STRIDE=64) --------------
__global__ __launch_bounds__(64) void flif_final_kernel(const float* __restrict__ Io,
                                                        float* __restrict__ spikes,
                                                        float* __restrict__ mems,
                                                        const float* __restrict__ ctab,
                                                        float kappa) {
    __shared__ float hist[T_STEPS * 64];                       // 32 KB
    __shared__ __attribute__((aligned(16))) float cs[192];
    __shared__ __attribute__((aligned(16))) char inps[T_STEPS * 64 * 4];  // 32 KB
    const int lane = threadIdx.x;
    const int nid  = blockIdx.x * 64 + lane;

#pragma unroll
    for (int q = 0; q < 32; ++q) {
        const float* g = Io +
            ((size_t)(q * 4 + (lane >> 4)) * NT_O + (size_t)blockIdx.x * 64 + (lane & 15) * 4);
        __builtin_amdgcn_global_load_lds((const __attribute__((address_space(1))) void*)g,
                                         (__attribute__((address_space(3))) void*)(inps + q * 1024),
                                         16, 0, 0);
    }
    for (int j = lane; j < 192; j += 64) cs[j] = ctab[j];
    __syncthreads();

    flif_scan_body<true, 64>(inps, hist, cs, spikes, mems, NT_O, nid, lane, kappa);
}

extern "C" void kernel_launch(void* const* d_in, const int* in_sizes, int n_in,
                              void* d_out, int out_size, void* d_ws, size_t ws_size,
                              hipStream_t stream) {
    const float* data = (const float*)d_in[0];   // [64][128][784]
    const float* Wh   = (const float*)d_in[1];   // [512][784]
    const float* Wo   = (const float*)d_in[2];   // [10][512]
    float* out = (float*)d_out;                  // f32: spikes then mems

    char* ws = (char*)d_ws;
    size_t off = 0;
    auto alloc = [&](size_t bytes) { void* p = ws + off; off += (bytes + 255) & ~255ull; return p; };
    __hip_bfloat16* Ab   = (__hip_bfloat16*)alloc((size_t)M1 * NIP * 2);  // 13.1 MB (b-major)
    __hip_bfloat16* Whb  = (__hip_bfloat16*)alloc((size_t)NH * NIP * 2);  // 0.8 MB
    __hip_bfloat16* Sh   = (__hip_bfloat16*)alloc((size_t)M1 * NH * 2);   // 8.4 MB
    float*          Io   = (float*)alloc((size_t)M1 * NO * 4);            // 0.33 MB
    float*          ctab = (float*)alloc(192 * 4);

    const float kappa = (float)(std::pow(0.1, 0.2) * std::tgamma(1.8));

    prep_kernel<<<6801, 256, 0, stream>>>(data, Wh, Ab, Whb, ctab);

    dim3 g1(BATCH, NH / 64, 1);     // (64, 8) = 512 blocks, 1 block/CU (2 passes)
    fused1_kernel<<<g1, 256, 0, stream>>>(Ab, Whb, Sh, ctab, kappa);

    gemm2_kernel<<<M1 / 16, 256, 0, stream>>>(Sh, Wo, Io);

    flif_final_kernel<<<NT_O / 64, 64, 0, stream>>>(Io, out, out + OUT_HALF, ctab, kappa);
}

// Round 20
// 57.438 us; speedup vs baseline: 1.2283x; 1.2283x over previous
//
#include <hip/hip_runtime.h>
#include <hip/hip_bf16.h>
#include <cmath>

#define T_STEPS 128
#define BATCH   64
#define NI      784
#define NIP     800      // padded K (25 * 32)
#define NH      512
#define NO      10
#define M1      (T_STEPS*BATCH)       // 8192
#define NT_H    (BATCH*NH)            // 32768
#define NT_O    (BATCH*NO)            // 640
#define OUT_HALF (T_STEPS*BATCH*NO)   // 81920
#define TB      8                     // time-tile for the scan

typedef __attribute__((ext_vector_type(8))) short short8;
typedef __attribute__((ext_vector_type(4))) float f32x4;
typedef __attribute__((ext_vector_type(8))) unsigned short u16x8;

static __device__ __forceinline__ unsigned short f2b_bits(float x) {
    __hip_bfloat16 h = __float2bfloat16(x);
    return *reinterpret_cast<unsigned short*>(&h);
}
static __device__ __forceinline__ float b2f_bits(unsigned short u) {
    union { unsigned int i; float f; } v; v.i = ((unsigned int)u) << 16; return v.f;
}

// --- R8 scan body (verbatim arithmetic), shared by fused1 and scanF ---------
template <bool FINAL, int STRIDE>
__device__ __forceinline__ void flif_scan_body(const char* __restrict__ inps,
                                               float* __restrict__ hist,
                                               const float* __restrict__ cs,
                                               void* __restrict__ spikes,
                                               float* __restrict__ mems,
                                               int NT, int nid, int li, float kappa) {
    float cn_[TB];
#pragma unroll
    for (int j = 0; j < TB; ++j) cn_[j] = cs[j];

    float V = -70.f;
    unsigned dvbits = 0u;

    for (int t = 0; t < T_STEPS / TB; ++t) {
        const int n0 = t * TB;

        // episode 1: batch input reads (pinned early)
        float Ivv[TB];
#pragma unroll
        for (int i = 0; i < TB; ++i) {
            if constexpr (FINAL) Ivv[i] = ((const float*)inps)[(n0 + i) * STRIDE + li];
            else                 Ivv[i] = __bfloat162float(((const __hip_bfloat16*)inps)[(n0 + i) * STRIDE + li]);
        }
        __builtin_amdgcn_sched_barrier(0);

        float old_[TB];
#pragma unroll
        for (int i = 0; i < TB; ++i) old_[i] = 0.f;

        // old-phase: skipped (bit-exactly) while history is all +0.0
        if (__any(dvbits != 0u)) {
            for (int k0 = 0; k0 < n0; k0 += TB) {
                float hv[TB];
                unsigned sb = 0u;
#pragma unroll
                for (int kk = 0; kk < TB; ++kk) {
                    hv[kk] = hist[(k0 + kk) * STRIDE + li];
                    sb |= __float_as_uint(hv[kk]);
                }
                if (__any(sb != 0u)) {
                    const int base = n0 - k0 - (TB - 1);   // >=1; base-1 multiple of 8
                    float cw[2 * TB];                      // cw[j] = c[base-1+j]
#pragma unroll
                    for (int q = 0; q < 4; ++q) {
                        const float4 cv = *reinterpret_cast<const float4*>(cs + (base - 1) + 4 * q);
                        cw[4 * q + 0] = cv.x; cw[4 * q + 1] = cv.y;
                        cw[4 * q + 2] = cv.z; cw[4 * q + 3] = cv.w;
                    }
#pragma unroll
                    for (int kk = 0; kk < TB; ++kk) {
#pragma unroll
                        for (int i = 0; i < TB; ++i)
                            old_[i] += hv[kk] * cw[TB - kk + i];
                    }
                }
            }
        }

        // episode 2: sequential phase, pure VALU + global stores
        float dvb[TB];
#pragma unroll
        for (int i = 0; i < TB; ++i) {
            const int nm1 = n0 + i;
            const float Iv = Ivv[i];
            const float f  = (-0.025f * (V + 70.f) + Iv) * 2.0f;   // /CM, CM=0.5
            const float Vn = kappa * f + V - old_[i];
            const bool  sp = (Vn >= -50.f);
            const float Vr = sp ? -70.f : Vn;
            const float dv = Vr - V;
            dvb[i] = dv;
            dvbits |= __float_as_uint(dv);
#pragma unroll
            for (int i2 = i + 1; i2 < TB; ++i2)
                old_[i2] += dv * cn_[i2 - i];
            if (FINAL) {
                ((float*)spikes)[(size_t)nm1 * NT + nid] = sp ? 1.f : 0.f;
                mems[(size_t)nm1 * NT + nid] = Vr;
            } else {
                ((__hip_bfloat16*)spikes)[(size_t)nm1 * NT + nid] = __float2bfloat16(sp ? 1.f : 0.f);
            }
            V = Vr;
        }

        // episode 3: batch hist writes
        __builtin_amdgcn_sched_barrier(0);
#pragma unroll
        for (int i = 0; i < TB; ++i)
            hist[(n0 + i) * STRIDE + li] = dvb[i];
        __builtin_amdgcn_sched_barrier(0);
    }
}

// --- prep: ctab init + pure streaming casts (R15 b-major, no permute) -------
__global__ __launch_bounds__(256) void prep_kernel(const float* __restrict__ data,
                                                   const float* __restrict__ Wh,
                                                   __hip_bfloat16* __restrict__ Ab,
                                                   __hip_bfloat16* __restrict__ Whb,
                                                   float* __restrict__ ctab) {
    const int bid = blockIdx.x;
    if (bid == 0) {
        const int j = threadIdx.x;
        if (j < 192) {
            double a = pow((double)(j + 1), 0.8);
            double b = pow((double)j, 0.8);
            ctab[j] = (float)(a - b);
        }
        return;
    }
    if (bid <= 6400) {
        const int idx = (bid - 1) * 256 + threadIdx.x;      // < M1*200 exactly
        const int r  = idx / 200;
        const int n4 = (idx - r * 200) * 4;
        ushort4 o;
        if (n4 < NI) {
            const float4 f = *reinterpret_cast<const float4*>(data + (size_t)r * NI + n4);
            o.x = f2b_bits(f.x); o.y = f2b_bits(f.y); o.z = f2b_bits(f.z); o.w = f2b_bits(f.w);
        } else {
            o.x = o.y = o.z = o.w = 0;
        }
        *reinterpret_cast<ushort4*>(Ab + (size_t)r * NIP + n4) = o;
    } else {
        const int idx = (bid - 6401) * 256 + threadIdx.x;   // < NH*200 exactly
        const int r  = idx / 200;
        const int n4 = (idx - r * 200) * 4;
        ushort4 o;
        if (n4 < NI) {
            const float4 f = *reinterpret_cast<const float4*>(Wh + (size_t)r * NI + n4);
            o.x = f2b_bits(f.x); o.y = f2b_bits(f.y); o.z = f2b_bits(f.z); o.w = f2b_bits(f.w);
        } else {
            o.x = o.y = o.z = o.w = 0;
        }
        *reinterpret_cast<ushort4*>(Whb + (size_t)r * NIP + n4) = o;
    }
}

// ---------------------------------------------------------------------------
// FUSED: GEMM1 + hidden scan (R17 config — session best, 57.5 us).
// Triple-buffered global_load_lds staging, depth-2 counted-vmcnt pipeline
// (tile t+1,t+2 in flight; wait vmcnt(3) per iter, never a full drain in
// the loop body), raw s_barrier per iter. hist aliases the dead staging
// region post-GEMM, guarded by two __syncthreads.
// ---------------------------------------------------------------------------
__global__ __launch_bounds__(256) void fused1_kernel(const __hip_bfloat16* __restrict__ A,
                                                     const __hip_bfloat16* __restrict__ B,
                                                     __hip_bfloat16* __restrict__ Sh,
                                                     const float* __restrict__ ctab,
                                                     float kappa) {
    __shared__ __attribute__((aligned(16))) char SMEM[54016];
    __hip_bfloat16* As   = (__hip_bfloat16*)SMEM;             // 3 bufs x 8KB: [0,24K)
    __hip_bfloat16* Bs   = (__hip_bfloat16*)(SMEM + 24576);   // 3 bufs x 4KB: [24K,36K)
    __hip_bfloat16* Ibuf = (__hip_bfloat16*)(SMEM + 36864);   // [36K,52K)  [t][h]
    float*          hist = (float*)SMEM;                      // [0,32K) post-GEMM (aliases staging)
    float*          cs   = (float*)(SMEM + 53248);            // [52K,52K+768)

    const int tid  = threadIdx.x;
    const int wave = tid >> 6, lane = tid & 63;
    const int wm = wave >> 1, wn = wave & 1;     // 2x2 waves over (128 t, 64 h)
    const int b  = blockIdx.x;                   // batch element
    const int hn = blockIdx.y;                   // 64-wide neuron block
    const int lrow = lane >> 2;      // 0..15
    const int lchk = lane & 3;       // 0..3

    const int NTILES = NIP / 32;     // 25

    auto STAGE = [&](int buf, int tt) {
        const int k0 = tt * 32;
#pragma unroll
        for (int p = 0; p < 2; ++p) {   // A tile 128x32: two stripes per wave
            const int rbase = p * 64 + wave * 16;
            const __hip_bfloat16* g = A + (size_t)(b * T_STEPS + rbase + lrow) * NIP + k0 + lchk * 8;
            __builtin_amdgcn_global_load_lds((const __attribute__((address_space(1))) void*)g,
                                             (__attribute__((address_space(3))) void*)(As + buf * (128 * 32) + rbase * 32),
                                             16, 0, 0);
        }
        {   // B tile 64x32: one stripe per wave
            const __hip_bfloat16* g = B + (size_t)(hn * 64 + wave * 16 + lrow) * NIP + k0 + lchk * 8;
            __builtin_amdgcn_global_load_lds((const __attribute__((address_space(1))) void*)g,
                                             (__attribute__((address_space(3))) void*)(Bs + buf * (64 * 32) + wave * 16 * 32),
                                             16, 0, 0);
        }
    };

    f32x4 acc[4][2] = {};

    // prologue: stage tiles 0..1; full drain once
    STAGE(0, 0);
    STAGE(1, 1);
    for (int j = tid; j < 192; j += 256) cs[j] = ctab[j];
    __syncthreads();                 // vmcnt(0) drain: tiles 0-1 landed; cs visible

    for (int t = 0; t < NTILES; ++t) {
        if (t + 2 < NTILES) STAGE((t + 2) % 3, t + 2);   // depth-2 prefetch in flight

        const int cur = t % 3;
        short8 a[4], bb[2];
#pragma unroll
        for (int i = 0; i < 4; ++i)
            a[i] = *reinterpret_cast<const short8*>(As + cur * (128 * 32) + (wm * 64 + i * 16 + (lane & 15)) * 32 + (lane >> 4) * 8);
#pragma unroll
        for (int j = 0; j < 2; ++j)
            bb[j] = *reinterpret_cast<const short8*>(Bs + cur * (64 * 32) + (wn * 32 + j * 16 + (lane & 15)) * 32 + (lane >> 4) * 8);
#pragma unroll
        for (int i = 0; i < 4; ++i)
#pragma unroll
            for (int j = 0; j < 2; ++j)
                acc[i][j] = __builtin_amdgcn_mfma_f32_16x16x32_bf16(a[i], bb[j], acc[i][j], 0, 0, 0);

        // end-of-iter: guarantee tile t+1 complete (counted, NOT a drain),
        // then barrier so all waves agree before buf (t+3)%3 is overwritten.
        if (t + 1 < NTILES) {
            if (t <= 22) asm volatile("s_waitcnt vmcnt(3)" ::: "memory");
            else         asm volatile("s_waitcnt vmcnt(0)" ::: "memory");
            __builtin_amdgcn_sched_barrier(0);
            __builtin_amdgcn_s_barrier();
            __builtin_amdgcn_sched_barrier(0);
        }
    }

    __syncthreads();   // all waves' K-loop reads complete before aliased writes

    // I tile -> LDS bf16 (same cast as before; row=t, col=h)
    // C/D layout: col = lane&15, row = (lane>>4)*4 + reg
#pragma unroll
    for (int i = 0; i < 4; ++i) {
#pragma unroll
        for (int j = 0; j < 2; ++j) {
            const int col = wn * 32 + j * 16 + (lane & 15);
#pragma unroll
            for (int r2 = 0; r2 < 4; ++r2) {
                const int row = wm * 64 + i * 16 + (lane >> 4) * 4 + r2;
                Ibuf[row * 64 + col] = __float2bfloat16(acc[i][j][r2]);
            }
        }
    }
    __syncthreads();                             // Ibuf complete; staging region dead

    // hidden scan: wave 0, one thread per neuron column (hist aliases staging).
    // Store: Sh[(t*64+b)*NH + hn*64 + lane] = (Sh+b*NH)[t*(64*NH) + hn*64+lane]
    if (tid < 64) {
        flif_scan_body<false, 64>((const char*)Ibuf, hist, cs,
                                  (void*)(Sh + (size_t)b * NH), nullptr,
                                  64 * NH, hn * 64 + tid, tid, kappa);
    }
}

// --- GEMM2: Io[r][o] = sum_h S[r][h]*Wo[o][h] (R8/R12 version) --------------
__global__ __launch_bounds__(256) void gemm2_kernel(const __hip_bfloat16* __restrict__ S,
                                                    const float* __restrict__ Wo,
                                                    float* __restrict__ Io) {
    const int wave = threadIdx.x >> 6, lane = threadIdx.x & 63;
    const int r0 = (blockIdx.x * 4 + wave) * 4;

    float wreg[NO][8];
#pragma unroll
    for (int o = 0; o < NO; ++o) {
        const float4 w0 = *reinterpret_cast<const float4*>(Wo + (size_t)o * NH + lane * 8);
        const float4 w1 = *reinterpret_cast<const float4*>(Wo + (size_t)o * NH + lane * 8 + 4);
        wreg[o][0] = w0.x; wreg[o][1] = w0.y; wreg[o][2] = w0.z; wreg[o][3] = w0.w;
        wreg[o][4] = w1.x; wreg[o][5] = w1.y; wreg[o][6] = w1.z; wreg[o][7] = w1.w;
    }

#pragma unroll
    for (int rr = 0; rr < 4; ++rr) {
        const int r = r0 + rr;
        u16x8 raw = *reinterpret_cast<const u16x8*>(S + (size_t)r * NH + lane * 8);
        float s[8];
#pragma unroll
        for (int j = 0; j < 8; ++j) s[j] = b2f_bits(raw[j]);
#pragma unroll
        for (int o = 0; o < NO; ++o) {
            float a = 0.f;
#pragma unroll
            for (int j = 0; j < 8; ++j) a += s[j] * wreg[o][j];
#pragma unroll
            for (int off = 32; off; off >>= 1) a += __shfl_xor(a, off);
            if (lane == o) Io[(size_t)r * NO + o] = a;
        }
    }
}

// --- final scan (R8/R12 version: LDS-staged f32 input, STRIDE=64) -----------
__global__ __launch_bounds__(64) void flif_final_kernel(const float* __restrict__ Io,
                                                        float* __restrict__ spikes,
                                                        float* __restrict__ mems,
                                                        const float* __restrict__ ctab,
                                                        float kappa) {
    __shared__ float hist[T_STEPS * 64];                       // 32 KB
    __shared__ __attribute__((aligned(16))) float cs[192];
    __shared__ __attribute__((aligned(16))) char inps[T_STEPS * 64 * 4];  // 32 KB
    const int lane = threadIdx.x;
    const int nid  = blockIdx.x * 64 + lane;

#pragma unroll
    for (int q = 0; q < 32; ++q) {
        const float* g = Io +
            ((size_t)(q * 4 + (lane >> 4)) * NT_O + (size_t)blockIdx.x * 64 + (lane & 15) * 4);
        __builtin_amdgcn_global_load_lds((const __attribute__((address_space(1))) void*)g,
                                         (__attribute__((address_space(3))) void*)(inps + q * 1024),
                                         16, 0, 0);
    }
    for (int j = lane; j < 192; j += 64) cs[j] = ctab[j];
    __syncthreads();

    flif_scan_body<true, 64>(inps, hist, cs, spikes, mems, NT_O, nid, lane, kappa);
}

extern "C" void kernel_launch(void* const* d_in, const int* in_sizes, int n_in,
                              void* d_out, int out_size, void* d_ws, size_t ws_size,
                              hipStream_t stream) {
    const float* data = (const float*)d_in[0];   // [64][128][784]
    const float* Wh   = (const float*)d_in[1];   // [512][784]
    const float* Wo   = (const float*)d_in[2];   // [10][512]
    float* out = (float*)d_out;                  // f32: spikes then mems

    char* ws = (char*)d_ws;
    size_t off = 0;
    auto alloc = [&](size_t bytes) { void* p = ws + off; off += (bytes + 255) & ~255ull; return p; };
    __hip_bfloat16* Ab   = (__hip_bfloat16*)alloc((size_t)M1 * NIP * 2);  // 13.1 MB (b-major)
    __hip_bfloat16* Whb  = (__hip_bfloat16*)alloc((size_t)NH * NIP * 2);  // 0.8 MB
    __hip_bfloat16* Sh   = (__hip_bfloat16*)alloc((size_t)M1 * NH * 2);   // 8.4 MB
    float*          Io   = (float*)alloc((size_t)M1 * NO * 4);            // 0.33 MB
    float*          ctab = (float*)alloc(192 * 4);

    const float kappa = (float)(std::pow(0.1, 0.2) * std::tgamma(1.8));

    prep_kernel<<<6801, 256, 0, stream>>>(data, Wh, Ab, Whb, ctab);

    dim3 g1(BATCH, NH / 64, 1);     // (64, 8) = 512 blocks
    fused1_kernel<<<g1, 256, 0, stream>>>(Ab, Whb, Sh, ctab, kappa);

    gemm2_kernel<<<M1 / 16, 256, 0, stream>>>(Sh, Wo, Io);

    flif_final_kernel<<<NT_O / 64, 64, 0, stream>>>(Io, out, out + OUT_HALF, ctab, kappa);
}